// Round 18
// baseline (282.943 us; speedup 1.0000x reference)
//
#include <hip/hip_runtime.h>
#include <cstdint>

#define N_NODES 20000
#define N_EDGES 100000
#define BN_EPS 1e-5f
#define SCAN_BLKS 79    // ceil(20000/256)

typedef __attribute__((ext_vector_type(8))) short short8;
typedef __attribute__((ext_vector_type(4))) float floatx4;
typedef __attribute__((ext_vector_type(2))) float float2v;

__device__ __forceinline__ float lrelu(float v) { return fmaxf(v, 0.1f * v); }
__device__ __forceinline__ float4 ld4(const float* p) { return *reinterpret_cast<const float4*>(p); }
__device__ __forceinline__ float2 ld2(const float* p) { return *reinterpret_cast<const float2*>(p); }

__device__ __forceinline__ void atomAddF(float* p, float v) {
#if defined(__HIP_DEVICE_COMPILE__)
    unsafeAtomicAdd(p, v);
#else
    atomicAdd(p, v);
#endif
}

// fp32 -> bf16 round-to-nearest-even
__device__ __forceinline__ unsigned short f2bf(float f) {
    union { float f; uint32_t u; } v; v.f = f;
    uint32_t r = v.u + 0x7fffu + ((v.u >> 16) & 1u);
    return (unsigned short)(r >> 16);
}
__device__ __forceinline__ uint32_t pack2(float a, float b) {
    return (uint32_t)f2bf(a) | ((uint32_t)f2bf(b) << 16);
}
__device__ __forceinline__ short8 pack8(float4 a, float4 b) {
    union { short8 s; uint32_t u[4]; } r;
    r.u[0] = pack2(a.x, a.y); r.u[1] = pack2(a.z, a.w);
    r.u[2] = pack2(b.x, b.y); r.u[3] = pack2(b.z, b.w);
    return r.s;
}

// ================= prep1 =================
__device__ void stats10_dev(const float* __restrict__ v, int rows, float* __restrict__ out,
                            int blk, int nblk, float* sh) {
    if (threadIdx.x < 20) sh[threadIdx.x] = 0.f;
    __syncthreads();
    int nf2 = rows * 5;
    int stride = nblk * 256;                 // nblk multiple of 5
    int g = blk * 256 + threadIdx.x;
    int c2 = g % 5;
    float s0 = 0.f, s1 = 0.f, q0 = 0.f, q1 = 0.f;
    const float2* p = reinterpret_cast<const float2*>(v);
    for (int i = g; i < nf2; i += stride) {
        float2 t = p[i];
        s0 += t.x; s1 += t.y; q0 += t.x * t.x; q1 += t.y * t.y;
    }
    atomicAdd(&sh[2 * c2], s0);
    atomicAdd(&sh[2 * c2 + 1], s1);
    atomicAdd(&sh[10 + 2 * c2], q0);
    atomicAdd(&sh[10 + 2 * c2 + 1], q1);
    __syncthreads();
    if (threadIdx.x < 20) atomAddF(&out[threadIdx.x], sh[threadIdx.x]);
}

__device__ void stats16_dev(const float* __restrict__ v, int rows, float* __restrict__ out,
                            int blk, int nblk, float* sh) {
    if (threadIdx.x < 32) sh[threadIdx.x] = 0.f;
    __syncthreads();
    int nf4 = rows * 4;
    int stride = nblk * 256;
    int g = blk * 256 + threadIdx.x;
    int cg = (g & 3) * 4;
    float s[4] = {0.f, 0.f, 0.f, 0.f}, q[4] = {0.f, 0.f, 0.f, 0.f};
    const float4* p = reinterpret_cast<const float4*>(v);
    for (int i = g; i < nf4; i += stride) {
        float4 t = p[i];
        s[0] += t.x; s[1] += t.y; s[2] += t.z; s[3] += t.w;
        q[0] += t.x * t.x; q[1] += t.y * t.y; q[2] += t.z * t.z; q[3] += t.w * t.w;
    }
    #pragma unroll
    for (int off = 32; off >= 4; off >>= 1) {
        #pragma unroll
        for (int j = 0; j < 4; ++j) {
            s[j] += __shfl_down(s[j], off, 64);
            q[j] += __shfl_down(q[j], off, 64);
        }
    }
    if ((threadIdx.x & 63) < 4) {
        #pragma unroll
        for (int j = 0; j < 4; ++j) {
            atomicAdd(&sh[cg + j], s[j]);
            atomicAdd(&sh[16 + cg + j], q[j]);
        }
    }
    __syncthreads();
    if (threadIdx.x < 32) atomAddF(&out[threadIdx.x], sh[threadIdx.x]);
}

// conv1 pack (bias in LDS), slice-major
template<int CIN, int COUT, int H, int OCH>
__device__ void convpack_row(const float* __restrict__ w2, const float* __restrict__ b2,
                             char* __restrict__ pk, int r) {
    constexpr int NROW = CIN * OCH;
    constexpr int WB = NROW * 64;
    constexpr int PACKB = WB + NROW * 4;
    if (r >= CIN * COUT) return;
    int chunk = r / NROW;
    int rem = r % NROW;
    int i = rem / OCH, ol = rem % OCH;
    int n = i * COUT + chunk * OCH + ol;
    char* base = pk + (size_t)chunk * PACKB;
    uint32_t pkv[16];
    #pragma unroll
    for (int t = 0; t < 16; ++t) pkv[t] = 0;
    #pragma unroll
    for (int k = 0; k < H; k += 2)
        pkv[k >> 1] = pack2(w2[(size_t)k * (CIN * COUT) + n],
                            w2[(size_t)(k + 1) * (CIN * COUT) + n]);
    uint4* ob = reinterpret_cast<uint4*>(base);
    #pragma unroll
    for (int q = 0; q < 4; ++q)
        ob[(size_t)q * NROW + rem] = make_uint4(pkv[4 * q], pkv[4 * q + 1],
                                                pkv[4 * q + 2], pkv[4 * q + 3]);
    ((float*)(base + WB))[rem] = b2[n];
}

// conv2 pack: weights-only (bias stays in global — 64 KB chunk fills static LDS)
template<int CIN, int COUT, int H, int OCH>
__device__ void convpack2w_row(const float* __restrict__ w2, char* __restrict__ pk, int r) {
    constexpr int NROW = CIN * OCH;
    constexpr int WB = NROW * 64;
    if (r >= CIN * COUT) return;
    int chunk = r / NROW;
    int rem = r % NROW;
    int i = rem / OCH, ol = rem % OCH;
    int n = i * COUT + chunk * OCH + ol;
    char* base = pk + (size_t)chunk * WB;
    uint32_t pkv[16];
    #pragma unroll
    for (int t = 0; t < 16; ++t) pkv[t] = 0;
    #pragma unroll
    for (int k = 0; k < H; k += 2)
        pkv[k >> 1] = pack2(w2[(size_t)k * (CIN * COUT) + n],
                            w2[(size_t)(k + 1) * (CIN * COUT) + n]);
    uint4* ob = reinterpret_cast<uint4*>(base);
    #pragma unroll
    for (int q = 0; q < 4; ++q)
        ob[(size_t)q * NROW + rem] = make_uint4(pkv[4 * q], pkv[4 * q + 1],
                                                pkv[4 * q + 2], pkv[4 * q + 3]);
}

#define P1_S10 120
#define P1_S16 120
__global__ __launch_bounds__(256)
void prep1_kernel(const float* __restrict__ e, const float* __restrict__ x,
                  float* __restrict__ stats_e, float* __restrict__ stats_x,
                  const int* __restrict__ dst, int* __restrict__ counts,
                  const float* __restrict__ nn1_w2, const float* __restrict__ nn1_b2, char* __restrict__ cpack1,
                  const float* __restrict__ nn2_w2, char* __restrict__ cpack2,
                  const float* __restrict__ mw1, unsigned short* __restrict__ w1t,
                  const float* __restrict__ mw2, const float* __restrict__ mb2,
                  const float* __restrict__ mw3, const float* __restrict__ mb3,
                  const float* __restrict__ mw4, const float* __restrict__ mb4,
                  const float* __restrict__ mw5, const float* __restrict__ mb5,
                  float* __restrict__ mlpw)
{
    __shared__ float sh[32];
    int b = blockIdx.x;
    if (b < P1_S10) {
        stats10_dev(e, N_EDGES, stats_e, b, P1_S10, sh);
    } else if (b < P1_S10 + P1_S16) {
        stats16_dev(x, N_NODES, stats_x, b - P1_S10, P1_S16, sh);
    } else if (b < 631) {
        int i = (b - 240) * 256 + threadIdx.x;
        if (i < N_EDGES) atomicAdd(&counts[dst[i]], 1);
    } else if (b < 633) {
        convpack_row<16, 32, 16, 32>(nn1_w2, nn1_b2, cpack1, (b - 631) * 256 + threadIdx.x);
    } else if (b < 641) {
        convpack2w_row<32, 64, 32, 32>(nn2_w2, cpack2, (b - 633) * 256 + threadIdx.x);
    } else {
        if (threadIdx.x < 64) {
            int o = threadIdx.x;
            for (int k = 0; k < 160; k += 2) {
                float a = (k < 138) ? mw1[(size_t)k * 64 + o] : 0.f;
                float c = (k + 1 < 138) ? mw1[(size_t)(k + 1) * 64 + o] : 0.f;
                *reinterpret_cast<uint32_t*>(w1t + (size_t)o * 160 + k) = pack2(a, c);
            }
        }
        for (int i = threadIdx.x; i < 2764; i += 256) {
            float v = 0.f;
            if (i < 2048) v = mw2[i];
            else if (i < 2560) v = mw3[i - 2048];
            else if (i < 2688) v = mw4[i - 2560];
            else if (i < 2704) v = mw5[i - 2688];
            else if (i < 2736) v = mb2[i - 2704];
            else if (i < 2752) v = mb3[i - 2736];
            else if (i < 2760) v = mb4[i - 2752];
            else if (i < 2762) v = mb5[i - 2760];
            mlpw[i] = v;
        }
    }
}

// ================= multi-block scan =================
__global__ __launch_bounds__(256)
void scanA_kernel(const int* __restrict__ counts, int* __restrict__ bsum, int n) {
    __shared__ int sh[4];
    int b = blockIdx.x, t = threadIdx.x;
    int i = b * 256 + t;
    int v = (i < n) ? counts[i] : 0;
    #pragma unroll
    for (int off = 32; off > 0; off >>= 1) v += __shfl_down(v, off, 64);
    if ((t & 63) == 0) sh[t >> 6] = v;
    __syncthreads();
    if (t == 0) bsum[b] = sh[0] + sh[1] + sh[2] + sh[3];
}

__global__ __launch_bounds__(256)
void scanC_kernel(const int* __restrict__ counts, const int* __restrict__ bsum,
                  int* __restrict__ starts, int* __restrict__ cursor, int n) {
    __shared__ int ws[4];
    __shared__ int bs[SCAN_BLKS];
    int b = blockIdx.x, t = threadIdx.x;
    if (t < SCAN_BLKS) bs[t] = bsum[t];
    int i = b * 256 + t;
    int val = (i < n) ? counts[i] : 0;
    int lane = t & 63, wv = t >> 6;
    int v = val;
    #pragma unroll
    for (int off = 1; off < 64; off <<= 1) {
        int u = __shfl_up(v, off, 64);
        if (lane >= off) v += u;
    }
    if (lane == 63) ws[wv] = v;
    __syncthreads();
    int woff = 0;
    for (int w = 0; w < wv; ++w) woff += ws[w];
    int boff = 0;
    for (int w = 0; w < b; ++w) boff += bs[w];
    int ex = boff + woff + v - val;
    if (i < n) { starts[i] = ex; cursor[i] = ex; }
}

// ================= prep2: normalize16 | scatter(epos) | hgen x2-split =================
#define P2_N16 1250
#define P2_SCAT 391
#define P2_HGEN 782
__global__ __launch_bounds__(256)
void prep2_kernel(const float* __restrict__ x, const float* __restrict__ stats_x,
                  const float* __restrict__ bn_node_g, const float* __restrict__ bn_node_b,
                  float* __restrict__ x_n,
                  const int* __restrict__ dst, int* __restrict__ cursor, int* __restrict__ epos,
                  const float* __restrict__ e, const float* __restrict__ stats_e,
                  const float* __restrict__ bn_edge_g, const float* __restrict__ bn_edge_b,
                  float* __restrict__ e_n,
                  const float* __restrict__ w1a, const float* __restrict__ b1a,
                  const float* __restrict__ w1b, const float* __restrict__ b1b,
                  unsigned short* __restrict__ h1, unsigned short* __restrict__ h2)
{
    int b = blockIdx.x;
    if (b < P2_N16) {
        int idx = b * 256 + threadIdx.x;
        if (idx >= N_NODES * 16) return;
        int c = idx & 15;
        float N = (float)N_NODES;
        float m = stats_x[c] / N;
        float var = stats_x[16 + c] / N - m * m;
        float sc = rsqrtf(var + BN_EPS) * bn_node_g[c];
        x_n[idx] = (x[idx] - m) * sc + bn_node_b[c];
    } else if (b < P2_N16 + P2_SCAT) {
        int i = (b - P2_N16) * 256 + threadIdx.x;
        if (i < N_EDGES) {
            int p = atomicAdd(&cursor[dst[i]], 1);
            epos[i] = p;
        }
    } else {
        int g = (b - P2_N16 - P2_SCAT) * 256 + threadIdx.x;
        if (g >= 2 * N_EDGES) return;
        int eg = g >> 1, hh = g & 1;
        float ev[10];
        float Ecnt = (float)N_EDGES;
        #pragma unroll
        for (int j = 0; j < 10; ++j) {
            float m = stats_e[j] / Ecnt;
            float var = stats_e[10 + j] / Ecnt - m * m;
            float sc = rsqrtf(var + BN_EPS) * bn_edge_g[j];
            ev[j] = (e[(size_t)eg * 10 + j] - m) * sc + bn_edge_b[j];
        }
        if (hh == 0) {
            #pragma unroll
            for (int j = 0; j < 10; ++j) e_n[(size_t)eg * 10 + j] = ev[j];
        }
        {   // h1 half
            uint32_t pk[4];
            #pragma unroll
            for (int pp = 0; pp < 4; ++pp) {
                int k = (hh * 4 + pp) * 2;
                float a0 = b1a[k], a1 = b1a[k + 1];
                #pragma unroll
                for (int j = 0; j < 10; ++j) {
                    a0 += ev[j] * w1a[j * 16 + k];
                    a1 += ev[j] * w1a[j * 16 + k + 1];
                }
                pk[pp] = pack2(lrelu(a0), lrelu(a1));
            }
            uint4* o = reinterpret_cast<uint4*>(h1 + (size_t)eg * 32);
            o[hh] = make_uint4(pk[0], pk[1], pk[2], pk[3]);
            o[2 + hh] = make_uint4(0, 0, 0, 0);
        }
        {   // h2 half
            uint32_t pk[8];
            #pragma unroll
            for (int pp = 0; pp < 8; ++pp) {
                int k = (hh * 8 + pp) * 2;
                float a0 = b1b[k], a1 = b1b[k + 1];
                #pragma unroll
                for (int j = 0; j < 10; ++j) {
                    a0 += ev[j] * w1b[j * 32 + k];
                    a1 += ev[j] * w1b[j * 32 + k + 1];
                }
                pk[pp] = pack2(lrelu(a0), lrelu(a1));
            }
            uint4* o = reinterpret_cast<uint4*>(h2 + (size_t)eg * 32);
            o[hh * 2]     = make_uint4(pk[0], pk[1], pk[2], pk[3]);
            o[hh * 2 + 1] = make_uint4(pk[4], pk[5], pk[6], pk[7]);
        }
    }
}

// ================= NNConv message kernel v8 =================
// GBIAS=true: 64 KB weight chunk fills static LDS; bias read from global (8 KB,
// L1-resident). r17 analysis: conv2 time tracks per-edge chunk replication (NCH),
// not LDS reads / block size / conflicts — so NCH 4->2 halves redundant bfrag/xr/
// src/epos traffic per edge.
template<int CIN, int COUT, int OCH, int NE, int IB, bool GBIAS, int WAVES>
__global__ __launch_bounds__(WAVES * 64, 4)
void conv_lds_kernel(const unsigned short* __restrict__ hbuf,
                     const char* __restrict__ pack,
                     const float* __restrict__ b2g,      // used when GBIAS
                     const int* __restrict__ src,
                     const int* __restrict__ epos,
                     const float* __restrict__ xin,
                     float* __restrict__ msgbuf,
                     int n_edges)
{
    constexpr int NCH = COUT / OCH;
    constexpr int NROW = CIN * OCH;
    constexpr int WB = NROW * 64;
    constexpr int PACKB = GBIAS ? WB : (WB + NROW * 4);
    constexpr int NOT = OCH / 16;
    __shared__ char smem[PACKB];

    int tid = threadIdx.x;
    int chunk = blockIdx.x % NCH;
    int eblk = blockIdx.x / NCH;

    {
        const uint4* g = reinterpret_cast<const uint4*>(pack + (size_t)chunk * PACKB);
        uint4* s = reinterpret_cast<uint4*>(smem);
        #pragma unroll 1
        for (int o = tid; o < PACKB / 16; o += WAVES * 64) s[o] = g[o];
    }
    __syncthreads();

    int wv = tid >> 6, lane = tid & 63;
    int el = lane & 15, quad = lane >> 4;
    int g0 = (eblk * WAVES + wv) * NE;
    if (g0 * 16 >= n_edges) return;

    const unsigned short* wlds = reinterpret_cast<const unsigned short*>(smem)
                                 + ((size_t)quad * NROW + el) * 8;
    const float* blds = GBIAS ? (b2g + chunk * OCH + quad * 4)
                              : (reinterpret_cast<const float*>(smem + WB) + quad * 4);

    int sg[NE], slot[NE];
    short8 bfrag[NE];
    #pragma unroll
    for (int g = 0; g < NE; ++g) {
        int e0 = (g0 + g) * 16;
        int e = (e0 < n_edges) ? (e0 + el) : el;
        sg[g] = src[e];
        slot[g] = epos[e];
        bfrag[g] = *reinterpret_cast<const short8*>(hbuf + (size_t)e * 32 + quad * 8);
    }

    float2v msg0[NE][NOT], msg1[NE][NOT];
    #pragma unroll
    for (int g = 0; g < NE; ++g)
        #pragma unroll
        for (int t = 0; t < NOT; ++t) {
            msg0[g][t] = (float2v){0.f, 0.f};
            msg1[g][t] = (float2v){0.f, 0.f};
        }

    const float2v pt = {0.1f, 0.1f};

    #pragma unroll 1
    for (int ib = 0; ib < CIN / IB; ++ib) {
        float xs[NE][IB];
        #pragma unroll
        for (int g = 0; g < NE; ++g) {
            #pragma unroll
            for (int t = 0; t < IB; t += 4) {
                float4 v = ld4(xin + (size_t)sg[g] * CIN + ib * IB + t);
                xs[g][t] = v.x; xs[g][t + 1] = v.y; xs[g][t + 2] = v.z; xs[g][t + 3] = v.w;
            }
        }
        #pragma unroll
        for (int ii = 0; ii < IB; ++ii) {
            int i = ib * IB + ii;
            #pragma unroll
            for (int ot = 0; ot < NOT; ++ot) {
                short8 af = *reinterpret_cast<const short8*>(wlds + (i * OCH + ot * 16) * 8);
                float4 bb = GBIAS ? ld4(blds + i * COUT + ot * 16)
                                  : *reinterpret_cast<const float4*>(blds + i * OCH + ot * 16);
                floatx4 cinit = {bb.x, bb.y, bb.z, bb.w};
                #pragma unroll
                for (int g = 0; g < NE; ++g) {
                    floatx4 c = __builtin_amdgcn_mfma_f32_16x16x32_bf16(af, bfrag[g], cinit, 0, 0, 0);
                    float2v c0 = {c[0], c[1]}, c1 = {c[2], c[3]};
                    float2v m0 = __builtin_elementwise_max(c0, c0 * pt);
                    float2v m1 = __builtin_elementwise_max(c1, c1 * pt);
                    float2v xi2 = {xs[g][ii], xs[g][ii]};
                    msg0[g][ot] += xi2 * m0;
                    msg1[g][ot] += xi2 * m1;
                }
            }
        }
    }

    #pragma unroll
    for (int g = 0; g < NE; ++g) {
        if ((g0 + g) * 16 >= n_edges) break;
        float* orow = msgbuf + (size_t)slot[g] * COUT + chunk * OCH;
        #pragma unroll
        for (int ot = 0; ot < NOT; ++ot)
            *reinterpret_cast<float4*>(orow + ot * 16 + quad * 4) =
                make_float4(msg0[g][ot][0], msg0[g][ot][1], msg1[g][ot][0], msg1[g][ot][1]);
    }
}

// ================= CSR gather (sequential rows) with fused root transform ============
template<int CIN, int C>
__global__ __launch_bounds__(256)
void gather_root_kernel(const float* __restrict__ xin, const float* __restrict__ w,
                        const float* __restrict__ bias,
                        const float* __restrict__ msg,
                        const int* __restrict__ starts, const int* __restrict__ counts,
                        float* __restrict__ xout, int nodes)
{
    constexpr int NPW = 64 / C;
    int wv = blockIdx.x * 4 + (threadIdx.x >> 6);
    int lane = threadIdx.x & 63;
    int node = wv * NPW + lane / C;
    int ch = lane % C;
    if (node >= nodes) return;
    float acc = bias[ch];
    const float* xrow = xin + (size_t)node * CIN;
    #pragma unroll
    for (int i = 0; i < CIN; ++i) acc += xrow[i] * w[i * C + ch];
    int s0 = starts[node], cnt = counts[node];
    const float* mrow = msg + (size_t)s0 * C + ch;
    int i = 0;
    for (; i + 3 < cnt; i += 4) {
        float m0 = mrow[(size_t)(i)     * C];
        float m1 = mrow[(size_t)(i + 1) * C];
        float m2 = mrow[(size_t)(i + 2) * C];
        float m3 = mrow[(size_t)(i + 3) * C];
        acc += (m0 + m1) + (m2 + m3);
    }
    for (; i < cnt; ++i) acc += mrow[(size_t)i * C];
    xout[(size_t)node * C + ch] = acc;
}

// ================= edge MLP v2: wave-synchronous, single barrier =================
__global__ __launch_bounds__(256)
void mlp2_kernel(const float* __restrict__ x2, const float* __restrict__ e_n,
                 const int* __restrict__ src, const int* __restrict__ dst,
                 const unsigned short* __restrict__ w1t, const float* __restrict__ b1,
                 const float* __restrict__ mlpw,
                 float* __restrict__ out, int n_edges)
{
    __shared__ float wl[2764];
    __shared__ float a1t[4 * 1092];
    __shared__ float a2scr[4 * 528];

    int tid = threadIdx.x;
    {
        const uint4* g = reinterpret_cast<const uint4*>(mlpw);
        uint4* s = reinterpret_cast<uint4*>(wl);
        #pragma unroll 1
        for (int i = tid; i < 691; i += 256) s[i] = g[i];
    }

    int wv = tid >> 6, lane = tid & 63;
    int el = lane & 15, quad = lane >> 4;
    int e = blockIdx.x * 64 + wv * 16 + el;
    int eS = (e < n_edges) ? e : (n_edges - 1);
    int sN = src[eS], dN = dst[eS];

    short8 bf[5];
    {
        const float* rs = x2 + (size_t)sN * 64 + quad * 8;
        const float* rd = x2 + (size_t)dN * 64 + quad * 8;
        bf[0] = pack8(ld4(rs), ld4(rs + 4));
        bf[1] = pack8(ld4(rs + 32), ld4(rs + 36));
        bf[2] = pack8(ld4(rd), ld4(rd + 4));
        bf[3] = pack8(ld4(rd + 32), ld4(rd + 36));
        union { short8 s; uint32_t u[4]; } t;
        t.u[0] = t.u[1] = t.u[2] = t.u[3] = 0;
        const float* ep = e_n + (size_t)eS * 10;
        if (quad == 0) {
            float2 p0 = ld2(ep), p1 = ld2(ep + 2), p2 = ld2(ep + 4), p3 = ld2(ep + 6);
            t.u[0] = pack2(p0.x, p0.y); t.u[1] = pack2(p1.x, p1.y);
            t.u[2] = pack2(p2.x, p2.y); t.u[3] = pack2(p3.x, p3.y);
        } else if (quad == 1) {
            float2 p4 = ld2(ep + 8);
            t.u[0] = pack2(p4.x, p4.y);
        }
        bf[4] = t.s;
    }

    float* slab = &a1t[wv * 1092];
    {
        floatx4 acc[4];
        #pragma unroll
        for (int ot = 0; ot < 4; ++ot) {
            float4 bb = ld4(b1 + ot * 16 + quad * 4);
            acc[ot] = (floatx4){bb.x, bb.y, bb.z, bb.w};
        }
        #pragma unroll
        for (int ks = 0; ks < 5; ++ks) {
            #pragma unroll
            for (int ot = 0; ot < 4; ++ot) {
                short8 af = *reinterpret_cast<const short8*>(
                    w1t + (size_t)(ot * 16 + el) * 160 + ks * 32 + quad * 8);
                acc[ot] = __builtin_amdgcn_mfma_f32_16x16x32_bf16(af, bf[ks], acc[ot], 0, 0, 0);
            }
        }
        #pragma unroll
        for (int ot = 0; ot < 4; ++ot) {
            #pragma unroll
            for (int r = 0; r < 4; ++r)
                slab[(ot * 16 + quad * 4 + r) * 17 + el] = lrelu(acc[ot][r]);
        }
    }
    __syncthreads();

    const float* w2l = wl;            const float* w3l = wl + 2048;
    const float* w4l = wl + 2560;     const float* w5l = wl + 2688;
    const float* b2l = wl + 2704;     const float* b3l = wl + 2736;
    const float* b4l = wl + 2752;     const float* b5l = wl + 2760;
    float* a2s = &a2scr[wv * 528];
    float* a3s = slab;
    float* a4s = slab + 512;
    int p = quad;

    {   // layer 2
        float a2[8];
        #pragma unroll
        for (int j = 0; j < 8; ++j) a2[j] = b2l[p * 8 + j];
        #pragma unroll 4
        for (int i = 0; i < 64; ++i) {
            float ai = slab[i * 17 + el];
            #pragma unroll
            for (int j = 0; j < 8; ++j) a2[j] += ai * w2l[i * 32 + p * 8 + j];
        }
        #pragma unroll
        for (int j = 0; j < 8; ++j) a2s[el * 33 + p * 8 + j] = lrelu(a2[j]);
    }
    {   // layer 3
        float a3[4];
        #pragma unroll
        for (int j = 0; j < 4; ++j) a3[j] = b3l[p * 4 + j];
        #pragma unroll 4
        for (int i = 0; i < 32; ++i) {
            float ai = a2s[el * 33 + i];
            #pragma unroll
            for (int j = 0; j < 4; ++j) a3[j] += ai * w3l[i * 16 + p * 4 + j];
        }
        #pragma unroll
        for (int j = 0; j < 4; ++j) a3s[el * 17 + p * 4 + j] = lrelu(a3[j]);
    }
    {   // layer 4
        float a4[2];
        a4[0] = b4l[p * 2]; a4[1] = b4l[p * 2 + 1];
        #pragma unroll
        for (int i = 0; i < 16; ++i) {
            float ai = a3s[el * 17 + i];
            a4[0] += ai * w4l[i * 8 + p * 2];
            a4[1] += ai * w4l[i * 8 + p * 2 + 1];
        }
        a4s[el * 9 + p * 2]     = lrelu(a4[0]);
        a4s[el * 9 + p * 2 + 1] = lrelu(a4[1]);
    }
    if (p < 2) {   // layer 5
        float o = b5l[p];
        #pragma unroll
        for (int i = 0; i < 8; ++i) o += a4s[el * 9 + i] * w5l[i * 2 + p];
        if (e < n_edges) out[(size_t)e * 2 + p] = o;
    }
}

// ================= launch =================
extern "C" void kernel_launch(void* const* d_in, const int* in_sizes, int n_in,
                              void* d_out, int out_size, void* d_ws, size_t ws_size,
                              hipStream_t stream)
{
    const float* x  = (const float*)d_in[0];
    const float* e  = (const float*)d_in[1];
    const int*   ei = (const int*)d_in[2];
    const float* bn_node_g = (const float*)d_in[4];
    const float* bn_node_b = (const float*)d_in[5];
    const float* bn_edge_g = (const float*)d_in[6];
    const float* bn_edge_b = (const float*)d_in[7];
    const float* nn1_w1 = (const float*)d_in[8];
    const float* nn1_b1 = (const float*)d_in[9];
    const float* nn1_w2 = (const float*)d_in[10];
    const float* nn1_b2 = (const float*)d_in[11];
    const float* nn2_w1 = (const float*)d_in[12];
    const float* nn2_b1 = (const float*)d_in[13];
    const float* nn2_w2 = (const float*)d_in[14];
    const float* nn2_b2 = (const float*)d_in[15];
    const float* l1_root = (const float*)d_in[16];
    const float* l1_bias = (const float*)d_in[17];
    const float* l2_root = (const float*)d_in[18];
    const float* l2_bias = (const float*)d_in[19];
    const float* mw1 = (const float*)d_in[20]; const float* mb1 = (const float*)d_in[21];
    const float* mw2 = (const float*)d_in[22]; const float* mb2 = (const float*)d_in[23];
    const float* mw3 = (const float*)d_in[24]; const float* mb3 = (const float*)d_in[25];
    const float* mw4 = (const float*)d_in[26]; const float* mb4 = (const float*)d_in[27];
    const float* mw5 = (const float*)d_in[28]; const float* mb5 = (const float*)d_in[29];

    const int* src = ei;
    const int* dst = ei + N_EDGES;

    float* ws = (float*)d_ws;
    float* stats_e = ws;                        // 20 (pad 32)
    float* stats_x = ws + 32;                   // 32
    int* counts = (int*)(ws + 64);              // 20000 (zeroed by memset)
    int* starts = counts + 20000;
    int* cursor = starts + 20000;
    int* epos   = cursor + 20000;               // 100000
    int* bsum   = epos + 100000;                // 128 (pad)
    float* e_n = ws + 64 + 160128;              // 1,000,000
    float* x_n = e_n + 1000000;                 //   320,000
    float* x1  = x_n + 320000;                  //   640,000
    float* x2  = x1 + 640000;                   // 1,280,000
    float* msg = x2 + 1280000;                  // 6,400,000 (CSR-ordered rows)
    unsigned short* h1   = (unsigned short*)(msg + 6400000);   // 100000*32 bf16
    unsigned short* h2   = h1 + 3200000;
    unsigned short* w1t  = h2 + 3200000;        // 64*160
    char* cpack1 = (char*)(w1t + 10240);        // 34816 B (bias appended)
    char* cpack2 = cpack1 + 34816;              // 2 * 65536 B (weights only)
    float* mlpw = (float*)(cpack2 + 2 * 65536); // 2764 floats
    float* out = (float*)d_out;

    (void)hipMemsetAsync(d_ws, 0, (64 + 20000) * 4, stream);

    prep1_kernel<<<642, 256, 0, stream>>>(
        e, x, stats_e, stats_x, dst, counts,
        nn1_w2, nn1_b2, cpack1, nn2_w2, cpack2,
        mw1, w1t, mw2, mb2, mw3, mb3, mw4, mb4, mw5, mb5, mlpw);

    scanA_kernel<<<SCAN_BLKS, 256, 0, stream>>>(counts, bsum, N_NODES);
    scanC_kernel<<<SCAN_BLKS, 256, 0, stream>>>(counts, bsum, starts, cursor, N_NODES);

    prep2_kernel<<<P2_N16 + P2_SCAT + P2_HGEN, 256, 0, stream>>>(
        x, stats_x, bn_node_g, bn_node_b, x_n,
        dst, cursor, epos,
        e, stats_e, bn_edge_g, bn_edge_b, e_n,
        nn1_w1, nn1_b1, nn2_w1, nn2_b1, h1, h2);

    const int NGRP = (N_EDGES + 15) / 16;               // 6250

    // conv1: NCH=1, 8 waves/block, NE=4 -> 196 blocks
    const int CB1 = (NGRP + 31) / 32;                   // 196
    conv_lds_kernel<16, 32, 32, 4, 4, false, 8><<<CB1, 512, 0, stream>>>(
        h1, cpack1, nullptr, src, epos, x_n, msg, N_EDGES);
    gather_root_kernel<16, 32><<<(N_NODES / 2 + 3) / 4, 256, 0, stream>>>(
        x_n, l1_root, l1_bias, msg, starts, counts, x1, N_NODES);

    // conv2: NCH=2 (OCH=32, 64 KB LDS, global bias), NE=2, 8 waves/block
    const int CB2 = (NGRP + 15) / 16;                   // 391 blocks per chunk
    conv_lds_kernel<32, 64, 32, 2, 8, true, 8><<<CB2 * 2, 512, 0, stream>>>(
        h2, cpack2, nn2_b2, src, epos, x1, msg, N_EDGES);
    gather_root_kernel<32, 64><<<(N_NODES + 3) / 4, 256, 0, stream>>>(
        x1, l2_root, l2_bias, msg, starts, counts, x2, N_NODES);

    mlp2_kernel<<<(N_EDGES + 63) / 64, 256, 0, stream>>>(
        x2, e_n, src, dst, w1t, mb1, mlpw, out, N_EDGES);
}

// Round 19
// 270.922 us; speedup vs baseline: 1.0444x; 1.0444x over previous
//
#include <hip/hip_runtime.h>
#include <cstdint>

#define N_NODES 20000
#define N_EDGES 100000
#define BN_EPS 1e-5f
#define SCAN_BLKS 79    // ceil(20000/256)

typedef __attribute__((ext_vector_type(8))) short short8;
typedef __attribute__((ext_vector_type(4))) float floatx4;
typedef __attribute__((ext_vector_type(2))) float float2v;

__device__ __forceinline__ float lrelu(float v) { return fmaxf(v, 0.1f * v); }
__device__ __forceinline__ float4 ld4(const float* p) { return *reinterpret_cast<const float4*>(p); }
__device__ __forceinline__ float2 ld2(const float* p) { return *reinterpret_cast<const float2*>(p); }

__device__ __forceinline__ void atomAddF(float* p, float v) {
#if defined(__HIP_DEVICE_COMPILE__)
    unsafeAtomicAdd(p, v);
#else
    atomicAdd(p, v);
#endif
}

// fp32 -> bf16 round-to-nearest-even
__device__ __forceinline__ unsigned short f2bf(float f) {
    union { float f; uint32_t u; } v; v.f = f;
    uint32_t r = v.u + 0x7fffu + ((v.u >> 16) & 1u);
    return (unsigned short)(r >> 16);
}
__device__ __forceinline__ uint32_t pack2(float a, float b) {
    return (uint32_t)f2bf(a) | ((uint32_t)f2bf(b) << 16);
}
__device__ __forceinline__ short8 pack8(float4 a, float4 b) {
    union { short8 s; uint32_t u[4]; } r;
    r.u[0] = pack2(a.x, a.y); r.u[1] = pack2(a.z, a.w);
    r.u[2] = pack2(b.x, b.y); r.u[3] = pack2(b.z, b.w);
    return r.s;
}

// ================= prep1: stats10 | stats16 | hist | convpack1 | convpack2 | wpack =====
__device__ void stats10_dev(const float* __restrict__ v, int rows, float* __restrict__ out,
                            int blk, int nblk, float* sh) {
    if (threadIdx.x < 20) sh[threadIdx.x] = 0.f;
    __syncthreads();
    int nf2 = rows * 5;
    int stride = nblk * 256;                 // nblk multiple of 5
    int g = blk * 256 + threadIdx.x;
    int c2 = g % 5;
    float s0 = 0.f, s1 = 0.f, q0 = 0.f, q1 = 0.f;
    const float2* p = reinterpret_cast<const float2*>(v);
    for (int i = g; i < nf2; i += stride) {
        float2 t = p[i];
        s0 += t.x; s1 += t.y; q0 += t.x * t.x; q1 += t.y * t.y;
    }
    atomicAdd(&sh[2 * c2], s0);
    atomicAdd(&sh[2 * c2 + 1], s1);
    atomicAdd(&sh[10 + 2 * c2], q0);
    atomicAdd(&sh[10 + 2 * c2 + 1], q1);
    __syncthreads();
    if (threadIdx.x < 20) atomAddF(&out[threadIdx.x], sh[threadIdx.x]);
}

__device__ void stats16_dev(const float* __restrict__ v, int rows, float* __restrict__ out,
                            int blk, int nblk, float* sh) {
    if (threadIdx.x < 32) sh[threadIdx.x] = 0.f;
    __syncthreads();
    int nf4 = rows * 4;
    int stride = nblk * 256;
    int g = blk * 256 + threadIdx.x;
    int cg = (g & 3) * 4;
    float s[4] = {0.f, 0.f, 0.f, 0.f}, q[4] = {0.f, 0.f, 0.f, 0.f};
    const float4* p = reinterpret_cast<const float4*>(v);
    for (int i = g; i < nf4; i += stride) {
        float4 t = p[i];
        s[0] += t.x; s[1] += t.y; s[2] += t.z; s[3] += t.w;
        q[0] += t.x * t.x; q[1] += t.y * t.y; q[2] += t.z * t.z; q[3] += t.w * t.w;
    }
    #pragma unroll
    for (int off = 32; off >= 4; off >>= 1) {
        #pragma unroll
        for (int j = 0; j < 4; ++j) {
            s[j] += __shfl_down(s[j], off, 64);
            q[j] += __shfl_down(q[j], off, 64);
        }
    }
    if ((threadIdx.x & 63) < 4) {
        #pragma unroll
        for (int j = 0; j < 4; ++j) {
            atomicAdd(&sh[cg + j], s[j]);
            atomicAdd(&sh[16 + cg + j], q[j]);
        }
    }
    __syncthreads();
    if (threadIdx.x < 32) atomAddF(&out[threadIdx.x], sh[threadIdx.x]);
}

// pack row r of conv weights, SLICE-MAJOR (conflict-free layout)
template<int CIN, int COUT, int H, int OCH>
__device__ void convpack_row(const float* __restrict__ w2, const float* __restrict__ b2,
                             char* __restrict__ pk, int r) {
    constexpr int NROW = CIN * OCH;
    constexpr int WB = NROW * 64;
    constexpr int PACKB = WB + NROW * 4;
    if (r >= CIN * COUT) return;
    int chunk = r / NROW;
    int rem = r % NROW;
    int i = rem / OCH, ol = rem % OCH;
    int n = i * COUT + chunk * OCH + ol;
    char* base = pk + (size_t)chunk * PACKB;
    uint32_t pkv[16];
    #pragma unroll
    for (int t = 0; t < 16; ++t) pkv[t] = 0;
    #pragma unroll
    for (int k = 0; k < H; k += 2)
        pkv[k >> 1] = pack2(w2[(size_t)k * (CIN * COUT) + n],
                            w2[(size_t)(k + 1) * (CIN * COUT) + n]);
    uint4* ob = reinterpret_cast<uint4*>(base);
    #pragma unroll
    for (int q = 0; q < 4; ++q)
        ob[(size_t)q * NROW + rem] = make_uint4(pkv[4 * q], pkv[4 * q + 1],
                                                pkv[4 * q + 2], pkv[4 * q + 3]);
    ((float*)(base + WB))[rem] = b2[n];
}

#define P1_S10 120
#define P1_S16 120
__global__ __launch_bounds__(256)
void prep1_kernel(const float* __restrict__ e, const float* __restrict__ x,
                  float* __restrict__ stats_e, float* __restrict__ stats_x,
                  const int* __restrict__ dst, int* __restrict__ counts,
                  const float* __restrict__ nn1_w2, const float* __restrict__ nn1_b2, char* __restrict__ cpack1,
                  const float* __restrict__ nn2_w2, const float* __restrict__ nn2_b2, char* __restrict__ cpack2,
                  const float* __restrict__ mw1, unsigned short* __restrict__ w1t,
                  const float* __restrict__ mw2, const float* __restrict__ mb2,
                  const float* __restrict__ mw3, const float* __restrict__ mb3,
                  const float* __restrict__ mw4, const float* __restrict__ mb4,
                  const float* __restrict__ mw5, const float* __restrict__ mb5,
                  float* __restrict__ mlpw)
{
    __shared__ float sh[32];
    int b = blockIdx.x;
    if (b < P1_S10) {
        stats10_dev(e, N_EDGES, stats_e, b, P1_S10, sh);
    } else if (b < P1_S10 + P1_S16) {
        stats16_dev(x, N_NODES, stats_x, b - P1_S10, P1_S16, sh);
    } else if (b < 631) {
        int i = (b - 240) * 256 + threadIdx.x;
        if (i < N_EDGES) atomicAdd(&counts[dst[i]], 1);
    } else if (b < 633) {
        convpack_row<16, 32, 16, 32>(nn1_w2, nn1_b2, cpack1, (b - 631) * 256 + threadIdx.x);
    } else if (b < 641) {
        convpack_row<32, 64, 32, 16>(nn2_w2, nn2_b2, cpack2, (b - 633) * 256 + threadIdx.x);
    } else {
        if (threadIdx.x < 64) {
            int o = threadIdx.x;
            for (int k = 0; k < 160; k += 2) {
                float a = (k < 138) ? mw1[(size_t)k * 64 + o] : 0.f;
                float c = (k + 1 < 138) ? mw1[(size_t)(k + 1) * 64 + o] : 0.f;
                *reinterpret_cast<uint32_t*>(w1t + (size_t)o * 160 + k) = pack2(a, c);
            }
        }
        for (int i = threadIdx.x; i < 2764; i += 256) {
            float v = 0.f;
            if (i < 2048) v = mw2[i];
            else if (i < 2560) v = mw3[i - 2048];
            else if (i < 2688) v = mw4[i - 2560];
            else if (i < 2704) v = mw5[i - 2688];
            else if (i < 2736) v = mb2[i - 2704];
            else if (i < 2752) v = mb3[i - 2736];
            else if (i < 2760) v = mb4[i - 2752];
            else if (i < 2762) v = mb5[i - 2760];
            mlpw[i] = v;
        }
    }
}

// ================= multi-block scan =================
__global__ __launch_bounds__(256)
void scanA_kernel(const int* __restrict__ counts, int* __restrict__ bsum, int n) {
    __shared__ int sh[4];
    int b = blockIdx.x, t = threadIdx.x;
    int i = b * 256 + t;
    int v = (i < n) ? counts[i] : 0;
    #pragma unroll
    for (int off = 32; off > 0; off >>= 1) v += __shfl_down(v, off, 64);
    if ((t & 63) == 0) sh[t >> 6] = v;
    __syncthreads();
    if (t == 0) bsum[b] = sh[0] + sh[1] + sh[2] + sh[3];
}

__global__ __launch_bounds__(256)
void scanC_kernel(const int* __restrict__ counts, const int* __restrict__ bsum,
                  int* __restrict__ starts, int* __restrict__ cursor, int n) {
    __shared__ int ws[4];
    __shared__ int bs[SCAN_BLKS];
    int b = blockIdx.x, t = threadIdx.x;
    if (t < SCAN_BLKS) bs[t] = bsum[t];
    int i = b * 256 + t;
    int val = (i < n) ? counts[i] : 0;
    int lane = t & 63, wv = t >> 6;
    int v = val;
    #pragma unroll
    for (int off = 1; off < 64; off <<= 1) {
        int u = __shfl_up(v, off, 64);
        if (lane >= off) v += u;
    }
    if (lane == 63) ws[wv] = v;
    __syncthreads();
    int woff = 0;
    for (int w = 0; w < wv; ++w) woff += ws[w];
    int boff = 0;
    for (int w = 0; w < b; ++w) boff += bs[w];
    int ex = boff + woff + v - val;
    if (i < n) { starts[i] = ex; cursor[i] = ex; }
}

// ================= prep2: normalize16 | scatter(epos) | hgen x2-split =================
#define P2_N16 1250
#define P2_SCAT 391
#define P2_HGEN 782
__global__ __launch_bounds__(256)
void prep2_kernel(const float* __restrict__ x, const float* __restrict__ stats_x,
                  const float* __restrict__ bn_node_g, const float* __restrict__ bn_node_b,
                  float* __restrict__ x_n,
                  const int* __restrict__ dst, int* __restrict__ cursor, int* __restrict__ epos,
                  const float* __restrict__ e, const float* __restrict__ stats_e,
                  const float* __restrict__ bn_edge_g, const float* __restrict__ bn_edge_b,
                  float* __restrict__ e_n,
                  const float* __restrict__ w1a, const float* __restrict__ b1a,
                  const float* __restrict__ w1b, const float* __restrict__ b1b,
                  unsigned short* __restrict__ h1, unsigned short* __restrict__ h2)
{
    int b = blockIdx.x;
    if (b < P2_N16) {
        int idx = b * 256 + threadIdx.x;
        if (idx >= N_NODES * 16) return;
        int c = idx & 15;
        float N = (float)N_NODES;
        float m = stats_x[c] / N;
        float var = stats_x[16 + c] / N - m * m;
        float sc = rsqrtf(var + BN_EPS) * bn_node_g[c];
        x_n[idx] = (x[idx] - m) * sc + bn_node_b[c];
    } else if (b < P2_N16 + P2_SCAT) {
        int i = (b - P2_N16) * 256 + threadIdx.x;
        if (i < N_EDGES) {
            int p = atomicAdd(&cursor[dst[i]], 1);
            epos[i] = p;
        }
    } else {
        int g = (b - P2_N16 - P2_SCAT) * 256 + threadIdx.x;
        if (g >= 2 * N_EDGES) return;
        int eg = g >> 1, hh = g & 1;
        float ev[10];
        float Ecnt = (float)N_EDGES;
        #pragma unroll
        for (int j = 0; j < 10; ++j) {
            float m = stats_e[j] / Ecnt;
            float var = stats_e[10 + j] / Ecnt - m * m;
            float sc = rsqrtf(var + BN_EPS) * bn_edge_g[j];
            ev[j] = (e[(size_t)eg * 10 + j] - m) * sc + bn_edge_b[j];
        }
        if (hh == 0) {
            #pragma unroll
            for (int j = 0; j < 10; ++j) e_n[(size_t)eg * 10 + j] = ev[j];
        }
        {   // h1 half
            uint32_t pk[4];
            #pragma unroll
            for (int pp = 0; pp < 4; ++pp) {
                int k = (hh * 4 + pp) * 2;
                float a0 = b1a[k], a1 = b1a[k + 1];
                #pragma unroll
                for (int j = 0; j < 10; ++j) {
                    a0 += ev[j] * w1a[j * 16 + k];
                    a1 += ev[j] * w1a[j * 16 + k + 1];
                }
                pk[pp] = pack2(lrelu(a0), lrelu(a1));
            }
            uint4* o = reinterpret_cast<uint4*>(h1 + (size_t)eg * 32);
            o[hh] = make_uint4(pk[0], pk[1], pk[2], pk[3]);
            o[2 + hh] = make_uint4(0, 0, 0, 0);
        }
        {   // h2 half
            uint32_t pk[8];
            #pragma unroll
            for (int pp = 0; pp < 8; ++pp) {
                int k = (hh * 8 + pp) * 2;
                float a0 = b1b[k], a1 = b1b[k + 1];
                #pragma unroll
                for (int j = 0; j < 10; ++j) {
                    a0 += ev[j] * w1b[j * 32 + k];
                    a1 += ev[j] * w1b[j * 32 + k + 1];
                }
                pk[pp] = pack2(lrelu(a0), lrelu(a1));
            }
            uint4* o = reinterpret_cast<uint4*>(h2 + (size_t)eg * 32);
            o[hh * 2]     = make_uint4(pk[0], pk[1], pk[2], pk[3]);
            o[hh * 2 + 1] = make_uint4(pk[4], pk[5], pk[6], pk[7]);
        }
    }
}

// ================= NNConv message kernel v6 (r16 champion config) =================
// Slice-major LDS weights+bias (conflict-free), lane-fixed bases, i-loop outer with
// NE=4 edge-groups inner (each af+bias ds_read feeds 4 MFMAs), 256-thread blocks.
template<int CIN, int COUT, int OCH, int NE, int IB>
__global__ __launch_bounds__(256, 4)
void conv_lds_kernel(const unsigned short* __restrict__ hbuf,
                     const char* __restrict__ pack,
                     const int* __restrict__ src,
                     const int* __restrict__ epos,
                     const float* __restrict__ xin,
                     float* __restrict__ msgbuf,
                     int n_edges)
{
    constexpr int NCH = COUT / OCH;
    constexpr int NROW = CIN * OCH;
    constexpr int WB = NROW * 64;
    constexpr int PACKB = WB + NROW * 4;
    constexpr int NOT = OCH / 16;
    __shared__ char smem[PACKB];

    int tid = threadIdx.x;
    int chunk = blockIdx.x % NCH;
    int eblk = blockIdx.x / NCH;

    {
        const uint4* g = reinterpret_cast<const uint4*>(pack + (size_t)chunk * PACKB);
        uint4* s = reinterpret_cast<uint4*>(smem);
        #pragma unroll 1
        for (int o = tid; o < PACKB / 16; o += 256) s[o] = g[o];
    }
    __syncthreads();

    int wv = tid >> 6, lane = tid & 63;
    int el = lane & 15, quad = lane >> 4;
    int g0 = (eblk * 4 + wv) * NE;
    if (g0 * 16 >= n_edges) return;

    const unsigned short* wlds = reinterpret_cast<const unsigned short*>(smem)
                                 + ((size_t)quad * NROW + el) * 8;
    const float* blds = reinterpret_cast<const float*>(smem + WB) + quad * 4;

    int sg[NE], slot[NE];
    short8 bfrag[NE];
    #pragma unroll
    for (int g = 0; g < NE; ++g) {
        int e0 = (g0 + g) * 16;
        int e = (e0 < n_edges) ? (e0 + el) : el;
        sg[g] = src[e];
        slot[g] = epos[e];
        bfrag[g] = *reinterpret_cast<const short8*>(hbuf + (size_t)e * 32 + quad * 8);
    }

    float2v msg0[NE][NOT], msg1[NE][NOT];
    #pragma unroll
    for (int g = 0; g < NE; ++g)
        #pragma unroll
        for (int t = 0; t < NOT; ++t) {
            msg0[g][t] = (float2v){0.f, 0.f};
            msg1[g][t] = (float2v){0.f, 0.f};
        }

    const float2v pt = {0.1f, 0.1f};

    #pragma unroll 1
    for (int ib = 0; ib < CIN / IB; ++ib) {
        float xs[NE][IB];
        #pragma unroll
        for (int g = 0; g < NE; ++g) {
            #pragma unroll
            for (int t = 0; t < IB; t += 4) {
                float4 v = ld4(xin + (size_t)sg[g] * CIN + ib * IB + t);
                xs[g][t] = v.x; xs[g][t + 1] = v.y; xs[g][t + 2] = v.z; xs[g][t + 3] = v.w;
            }
        }
        #pragma unroll
        for (int ii = 0; ii < IB; ++ii) {
            int i = ib * IB + ii;
            #pragma unroll
            for (int ot = 0; ot < NOT; ++ot) {
                short8 af = *reinterpret_cast<const short8*>(wlds + (i * OCH + ot * 16) * 8);
                float4 bb = *reinterpret_cast<const float4*>(blds + i * OCH + ot * 16);
                floatx4 cinit = {bb.x, bb.y, bb.z, bb.w};
                #pragma unroll
                for (int g = 0; g < NE; ++g) {
                    floatx4 c = __builtin_amdgcn_mfma_f32_16x16x32_bf16(af, bfrag[g], cinit, 0, 0, 0);
                    float2v c0 = {c[0], c[1]}, c1 = {c[2], c[3]};
                    float2v m0 = __builtin_elementwise_max(c0, c0 * pt);
                    float2v m1 = __builtin_elementwise_max(c1, c1 * pt);
                    float2v xi2 = {xs[g][ii], xs[g][ii]};
                    msg0[g][ot] += xi2 * m0;
                    msg1[g][ot] += xi2 * m1;
                }
            }
        }
    }

    #pragma unroll
    for (int g = 0; g < NE; ++g) {
        if ((g0 + g) * 16 >= n_edges) break;
        float* orow = msgbuf + (size_t)slot[g] * COUT + chunk * OCH;
        #pragma unroll
        for (int ot = 0; ot < NOT; ++ot)
            *reinterpret_cast<float4*>(orow + ot * 16 + quad * 4) =
                make_float4(msg0[g][ot][0], msg0[g][ot][1], msg1[g][ot][0], msg1[g][ot][1]);
    }
}

// ================= CSR gather (sequential rows) with fused root transform ============
template<int CIN, int C>
__global__ __launch_bounds__(256)
void gather_root_kernel(const float* __restrict__ xin, const float* __restrict__ w,
                        const float* __restrict__ bias,
                        const float* __restrict__ msg,
                        const int* __restrict__ starts, const int* __restrict__ counts,
                        float* __restrict__ xout, int nodes)
{
    constexpr int NPW = 64 / C;
    int wv = blockIdx.x * 4 + (threadIdx.x >> 6);
    int lane = threadIdx.x & 63;
    int node = wv * NPW + lane / C;
    int ch = lane % C;
    if (node >= nodes) return;
    float acc = bias[ch];
    const float* xrow = xin + (size_t)node * CIN;
    #pragma unroll
    for (int i = 0; i < CIN; ++i) acc += xrow[i] * w[i * C + ch];
    int s0 = starts[node], cnt = counts[node];
    const float* mrow = msg + (size_t)s0 * C + ch;
    int i = 0;
    for (; i + 3 < cnt; i += 4) {
        float m0 = mrow[(size_t)(i)     * C];
        float m1 = mrow[(size_t)(i + 1) * C];
        float m2 = mrow[(size_t)(i + 2) * C];
        float m3 = mrow[(size_t)(i + 3) * C];
        acc += (m0 + m1) + (m2 + m3);
    }
    for (; i < cnt; ++i) acc += mrow[(size_t)i * C];
    xout[(size_t)node * C + ch] = acc;
}

// ================= edge MLP v2: wave-synchronous, single barrier =================
__global__ __launch_bounds__(256)
void mlp2_kernel(const float* __restrict__ x2, const float* __restrict__ e_n,
                 const int* __restrict__ src, const int* __restrict__ dst,
                 const unsigned short* __restrict__ w1t, const float* __restrict__ b1,
                 const float* __restrict__ mlpw,
                 float* __restrict__ out, int n_edges)
{
    __shared__ float wl[2764];
    __shared__ float a1t[4 * 1092];
    __shared__ float a2scr[4 * 528];

    int tid = threadIdx.x;
    {
        const uint4* g = reinterpret_cast<const uint4*>(mlpw);
        uint4* s = reinterpret_cast<uint4*>(wl);
        #pragma unroll 1
        for (int i = tid; i < 691; i += 256) s[i] = g[i];
    }

    int wv = tid >> 6, lane = tid & 63;
    int el = lane & 15, quad = lane >> 4;
    int e = blockIdx.x * 64 + wv * 16 + el;
    int eS = (e < n_edges) ? e : (n_edges - 1);
    int sN = src[eS], dN = dst[eS];

    short8 bf[5];
    {
        const float* rs = x2 + (size_t)sN * 64 + quad * 8;
        const float* rd = x2 + (size_t)dN * 64 + quad * 8;
        bf[0] = pack8(ld4(rs), ld4(rs + 4));
        bf[1] = pack8(ld4(rs + 32), ld4(rs + 36));
        bf[2] = pack8(ld4(rd), ld4(rd + 4));
        bf[3] = pack8(ld4(rd + 32), ld4(rd + 36));
        union { short8 s; uint32_t u[4]; } t;
        t.u[0] = t.u[1] = t.u[2] = t.u[3] = 0;
        const float* ep = e_n + (size_t)eS * 10;
        if (quad == 0) {
            float2 p0 = ld2(ep), p1 = ld2(ep + 2), p2 = ld2(ep + 4), p3 = ld2(ep + 6);
            t.u[0] = pack2(p0.x, p0.y); t.u[1] = pack2(p1.x, p1.y);
            t.u[2] = pack2(p2.x, p2.y); t.u[3] = pack2(p3.x, p3.y);
        } else if (quad == 1) {
            float2 p4 = ld2(ep + 8);
            t.u[0] = pack2(p4.x, p4.y);
        }
        bf[4] = t.s;
    }

    float* slab = &a1t[wv * 1092];
    {
        floatx4 acc[4];
        #pragma unroll
        for (int ot = 0; ot < 4; ++ot) {
            float4 bb = ld4(b1 + ot * 16 + quad * 4);
            acc[ot] = (floatx4){bb.x, bb.y, bb.z, bb.w};
        }
        #pragma unroll
        for (int ks = 0; ks < 5; ++ks) {
            #pragma unroll
            for (int ot = 0; ot < 4; ++ot) {
                short8 af = *reinterpret_cast<const short8*>(
                    w1t + (size_t)(ot * 16 + el) * 160 + ks * 32 + quad * 8);
                acc[ot] = __builtin_amdgcn_mfma_f32_16x16x32_bf16(af, bf[ks], acc[ot], 0, 0, 0);
            }
        }
        #pragma unroll
        for (int ot = 0; ot < 4; ++ot) {
            #pragma unroll
            for (int r = 0; r < 4; ++r)
                slab[(ot * 16 + quad * 4 + r) * 17 + el] = lrelu(acc[ot][r]);
        }
    }
    __syncthreads();

    const float* w2l = wl;            const float* w3l = wl + 2048;
    const float* w4l = wl + 2560;     const float* w5l = wl + 2688;
    const float* b2l = wl + 2704;     const float* b3l = wl + 2736;
    const float* b4l = wl + 2752;     const float* b5l = wl + 2760;
    float* a2s = &a2scr[wv * 528];
    float* a3s = slab;
    float* a4s = slab + 512;
    int p = quad;

    {   // layer 2
        float a2[8];
        #pragma unroll
        for (int j = 0; j < 8; ++j) a2[j] = b2l[p * 8 + j];
        #pragma unroll 4
        for (int i = 0; i < 64; ++i) {
            float ai = slab[i * 17 + el];
            #pragma unroll
            for (int j = 0; j < 8; ++j) a2[j] += ai * w2l[i * 32 + p * 8 + j];
        }
        #pragma unroll
        for (int j = 0; j < 8; ++j) a2s[el * 33 + p * 8 + j] = lrelu(a2[j]);
    }
    {   // layer 3
        float a3[4];
        #pragma unroll
        for (int j = 0; j < 4; ++j) a3[j] = b3l[p * 4 + j];
        #pragma unroll 4
        for (int i = 0; i < 32; ++i) {
            float ai = a2s[el * 33 + i];
            #pragma unroll
            for (int j = 0; j < 4; ++j) a3[j] += ai * w3l[i * 16 + p * 4 + j];
        }
        #pragma unroll
        for (int j = 0; j < 4; ++j) a3s[el * 17 + p * 4 + j] = lrelu(a3[j]);
    }
    {   // layer 4
        float a4[2];
        a4[0] = b4l[p * 2]; a4[1] = b4l[p * 2 + 1];
        #pragma unroll
        for (int i = 0; i < 16; ++i) {
            float ai = a3s[el * 17 + i];
            a4[0] += ai * w4l[i * 8 + p * 2];
            a4[1] += ai * w4l[i * 8 + p * 2 + 1];
        }
        a4s[el * 9 + p * 2]     = lrelu(a4[0]);
        a4s[el * 9 + p * 2 + 1] = lrelu(a4[1]);
    }
    if (p < 2) {   // layer 5
        float o = b5l[p];
        #pragma unroll
        for (int i = 0; i < 8; ++i) o += a4s[el * 9 + i] * w5l[i * 2 + p];
        if (e < n_edges) out[(size_t)e * 2 + p] = o;
    }
}

// ================= launch =================
extern "C" void kernel_launch(void* const* d_in, const int* in_sizes, int n_in,
                              void* d_out, int out_size, void* d_ws, size_t ws_size,
                              hipStream_t stream)
{
    const float* x  = (const float*)d_in[0];
    const float* e  = (const float*)d_in[1];
    const int*   ei = (const int*)d_in[2];
    const float* bn_node_g = (const float*)d_in[4];
    const float* bn_node_b = (const float*)d_in[5];
    const float* bn_edge_g = (const float*)d_in[6];
    const float* bn_edge_b = (const float*)d_in[7];
    const float* nn1_w1 = (const float*)d_in[8];
    const float* nn1_b1 = (const float*)d_in[9];
    const float* nn1_w2 = (const float*)d_in[10];
    const float* nn1_b2 = (const float*)d_in[11];
    const float* nn2_w1 = (const float*)d_in[12];
    const float* nn2_b1 = (const float*)d_in[13];
    const float* nn2_w2 = (const float*)d_in[14];
    const float* nn2_b2 = (const float*)d_in[15];
    const float* l1_root = (const float*)d_in[16];
    const float* l1_bias = (const float*)d_in[17];
    const float* l2_root = (const float*)d_in[18];
    const float* l2_bias = (const float*)d_in[19];
    const float* mw1 = (const float*)d_in[20]; const float* mb1 = (const float*)d_in[21];
    const float* mw2 = (const float*)d_in[22]; const float* mb2 = (const float*)d_in[23];
    const float* mw3 = (const float*)d_in[24]; const float* mb3 = (const float*)d_in[25];
    const float* mw4 = (const float*)d_in[26]; const float* mb4 = (const float*)d_in[27];
    const float* mw5 = (const float*)d_in[28]; const float* mb5 = (const float*)d_in[29];

    const int* src = ei;
    const int* dst = ei + N_EDGES;

    float* ws = (float*)d_ws;
    float* stats_e = ws;                        // 20 (pad 32)
    float* stats_x = ws + 32;                   // 32
    int* counts = (int*)(ws + 64);              // 20000 (zeroed by memset)
    int* starts = counts + 20000;
    int* cursor = starts + 20000;
    int* epos   = cursor + 20000;               // 100000
    int* bsum   = epos + 100000;                // 128 (pad)
    float* e_n = ws + 64 + 160128;              // 1,000,000
    float* x_n = e_n + 1000000;                 //   320,000
    float* x1  = x_n + 320000;                  //   640,000
    float* x2  = x1 + 640000;                   // 1,280,000
    float* msg = x2 + 1280000;                  // 6,400,000 (CSR-ordered rows)
    unsigned short* h1   = (unsigned short*)(msg + 6400000);   // 100000*32 bf16
    unsigned short* h2   = h1 + 3200000;
    unsigned short* w1t  = h2 + 3200000;        // 64*160
    char* cpack1 = (char*)(w1t + 10240);        // 34816 B
    char* cpack2 = cpack1 + 34816;              // 4*34816 B
    float* mlpw = (float*)(cpack2 + 4 * 34816); // 2764 floats
    float* out = (float*)d_out;

    (void)hipMemsetAsync(d_ws, 0, (64 + 20000) * 4, stream);

    prep1_kernel<<<642, 256, 0, stream>>>(
        e, x, stats_e, stats_x, dst, counts,
        nn1_w2, nn1_b2, cpack1, nn2_w2, nn2_b2, cpack2,
        mw1, w1t, mw2, mb2, mw3, mb3, mw4, mb4, mw5, mb5, mlpw);

    scanA_kernel<<<SCAN_BLKS, 256, 0, stream>>>(counts, bsum, N_NODES);
    scanC_kernel<<<SCAN_BLKS, 256, 0, stream>>>(counts, bsum, starts, cursor, N_NODES);

    prep2_kernel<<<P2_N16 + P2_SCAT + P2_HGEN, 256, 0, stream>>>(
        x, stats_x, bn_node_g, bn_node_b, x_n,
        dst, cursor, epos,
        e, stats_e, bn_edge_g, bn_edge_b, e_n,
        nn1_w1, nn1_b1, nn2_w1, nn2_b1, h1, h2);

    const int NGRP = (N_EDGES + 15) / 16;               // 6250
    const int CB = (NGRP + 15) / 16;                    // 391 blocks per chunk

    conv_lds_kernel<16, 32, 32, 4, 4><<<CB, 256, 0, stream>>>(h1, cpack1, src, epos, x_n, msg, N_EDGES);
    gather_root_kernel<16, 32><<<(N_NODES / 2 + 3) / 4, 256, 0, stream>>>(
        x_n, l1_root, l1_bias, msg, starts, counts, x1, N_NODES);

    conv_lds_kernel<32, 64, 16, 4, 8><<<CB * 4, 256, 0, stream>>>(h2, cpack2, src, epos, x1, msg, N_EDGES);
    gather_root_kernel<32, 64><<<(N_NODES + 3) / 4, 256, 0, stream>>>(
        x1, l2_root, l2_bias, msg, starts, counts, x2, N_NODES);

    mlp2_kernel<<<(N_EDGES + 63) / 64, 256, 0, stream>>>(
        x2, e_n, src, dst, w1t, mb1, mlpw, out, N_EDGES);
}